// Round 1
// baseline (385.721 us; speedup 1.0000x reference)
//
#include <hip/hip_runtime.h>
#include <hip/hip_bf16.h>

#define B_ 8
#define N_ 1024
#define H_ 8
#define D_ 64

typedef __attribute__((ext_vector_type(8))) short short8;
typedef __attribute__((ext_vector_type(4))) float f32x4;

// ---------------------------------------------------------------------------
// Kernel 1: per (b,h): column norms over N -> energy[n]; row norms -> w_unit
// (bf16) into workspace.  One block per (b,h), 256 threads.
// q layout: [B, N, H, D]; for fixed (b,h): row n at qb + n*H*D, contiguous D.
// ---------------------------------------------------------------------------
__global__ __launch_bounds__(256) void k_stats(const float* __restrict__ q,
                                               ushort* __restrict__ wunit,
                                               float* __restrict__ energy) {
    const int bh = blockIdx.x;
    const int b = bh >> 3, h = bh & 7;
    const float* qb = q + (size_t)(b * N_ * H_ + h) * D_;
    __shared__ float red[16][64];
    __shared__ float inv2[64];
    const int t = threadIdx.x;
    const int dg = (t & 15) * 4;   // 4 consecutive d
    const int ng = t >> 4;         // 0..15

    // Phase A: column sums of squares (over token dim)
    float ax = 0.f, ay = 0.f, az = 0.f, aw = 0.f;
    for (int n = ng; n < N_; n += 16) {
        const float4 v = *(const float4*)(qb + (size_t)n * (H_ * D_) + dg);
        ax += v.x * v.x; ay += v.y * v.y; az += v.z * v.z; aw += v.w * v.w;
    }
    red[ng][dg + 0] = ax; red[ng][dg + 1] = ay;
    red[ng][dg + 2] = az; red[ng][dg + 3] = aw;
    __syncthreads();
    if (t < 64) {
        float s = 0.f;
        #pragma unroll
        for (int i = 0; i < 16; ++i) s += red[i][t];
        // denom = max(sqrt(s), 1e-12); 1/denom^2 == 1/max(s, 1e-24)
        inv2[t] = 1.0f / fmaxf(s, 1e-24f);
    }
    __syncthreads();

    // Phase B: per-row energy + row-normalized bf16 w_unit
    for (int n = t; n < N_; n += 256) {
        const float4* row = (const float4*)(qb + (size_t)n * (H_ * D_));
        float se = 0.f, sr = 0.f;
        #pragma unroll
        for (int i = 0; i < 16; ++i) {
            const float4 v = row[i];
            se += v.x * v.x * inv2[i * 4 + 0] + v.y * v.y * inv2[i * 4 + 1] +
                  v.z * v.z * inv2[i * 4 + 2] + v.w * v.w * inv2[i * 4 + 3];
            sr += v.x * v.x + v.y * v.y + v.z * v.z + v.w * v.w;
        }
        energy[(size_t)bh * N_ + n] = se;
        const float invr = 1.0f / fmaxf(sqrtf(sr), 1e-12f);
        __hip_bfloat162* wrow =
            (__hip_bfloat162*)(wunit + ((size_t)bh * N_ + n) * D_);
        #pragma unroll
        for (int i = 0; i < 16; ++i) {
            const float4 v = row[i];
            wrow[i * 2 + 0] =
                __float22bfloat162_rn(make_float2(v.x * invr, v.y * invr));
            wrow[i * 2 + 1] =
                __float22bfloat162_rn(make_float2(v.z * invr, v.w * invr));
        }
    }
}

// ---------------------------------------------------------------------------
// Kernel 2: softmax over head dim (8 values) per (b,n).
// ---------------------------------------------------------------------------
__global__ __launch_bounds__(256) void k_pi(const float* __restrict__ energy,
                                            const float* __restrict__ temp,
                                            float* __restrict__ Pi) {
    const int idx = blockIdx.x * 256 + threadIdx.x;  // [0, B*N)
    const int b = idx >> 10, n = idx & (N_ - 1);
    float e[H_];
    float m = -1e30f;
    #pragma unroll
    for (int h = 0; h < H_; ++h) {
        e[h] = energy[((size_t)(b * H_ + h)) * N_ + n] * temp[h];
        m = fmaxf(m, e[h]);
    }
    float s = 0.f;
    #pragma unroll
    for (int h = 0; h < H_; ++h) { e[h] = expf(e[h] - m); s += e[h]; }
    const float inv = 1.0f / s;
    #pragma unroll
    for (int h = 0; h < H_; ++h)
        Pi[((size_t)(b * H_ + h)) * N_ + n] = e[h] * inv;
}

// ---------------------------------------------------------------------------
// Kernel 3: per (b,h): S = sum Pi; dots[d] = (sum Pi*w^2)/(S+eps);
// attn = 1/(1+dots); out = -(w*Pi)*attn.  One block per (b,h).
// ---------------------------------------------------------------------------
__global__ __launch_bounds__(256) void k_out(const float* __restrict__ q,
                                             const float* __restrict__ Pi,
                                             float* __restrict__ out0) {
    const int bh = blockIdx.x;
    const int b = bh >> 3, h = bh & 7;
    const float* qb = q + (size_t)(b * N_ * H_ + h) * D_;
    const float* Pib = Pi + (size_t)bh * N_;
    __shared__ float red[16][64];
    __shared__ float attnv[64];
    __shared__ float rbuf[256];
    const int t = threadIdx.x;

    // S = sum_n Pi[n]
    float s = 0.f;
    for (int n = t; n < N_; n += 256) s += Pib[n];
    rbuf[t] = s;
    __syncthreads();
    if (t < 64) {
        s = rbuf[t] + rbuf[t + 64] + rbuf[t + 128] + rbuf[t + 192];
        #pragma unroll
        for (int off = 32; off > 0; off >>= 1) s += __shfl_down(s, off);
        if (t == 0) rbuf[0] = 1.0f / (s + 1e-8f);
    }
    __syncthreads();
    const float invS = rbuf[0];

    // dots
    const int dg = (t & 15) * 4;
    const int ng = t >> 4;
    float ax = 0.f, ay = 0.f, az = 0.f, aw = 0.f;
    for (int n = ng; n < N_; n += 16) {
        const float p = Pib[n];
        const float4 v = *(const float4*)(qb + (size_t)n * (H_ * D_) + dg);
        ax += p * v.x * v.x; ay += p * v.y * v.y;
        az += p * v.z * v.z; aw += p * v.w * v.w;
    }
    red[ng][dg + 0] = ax; red[ng][dg + 1] = ay;
    red[ng][dg + 2] = az; red[ng][dg + 3] = aw;
    __syncthreads();
    if (t < 64) {
        float d2 = 0.f;
        #pragma unroll
        for (int i = 0; i < 16; ++i) d2 += red[i][t];
        attnv[t] = 1.0f / (1.0f + d2 * invS);
    }
    __syncthreads();

    // out write (same addressing pattern as q rows)
    for (int n = t; n < N_; n += 256) {
        const float p = -Pib[n];
        const float4* row = (const float4*)(qb + (size_t)n * (H_ * D_));
        float4* orow = (float4*)(out0 + ((size_t)(b * N_ + n) * H_ + h) * D_);
        #pragma unroll
        for (int i = 0; i < 16; ++i) {
            const float4 v = row[i];
            orow[i] = make_float4(v.x * p * attnv[i * 4 + 0],
                                  v.y * p * attnv[i * 4 + 1],
                                  v.z * p * attnv[i * 4 + 2],
                                  v.w * p * attnv[i * 4 + 3]);
        }
    }
}

// ---------------------------------------------------------------------------
// Kernel 4: gram matrix (w_unit @ w_unit^T + 1) * 0.5 via bf16 MFMA.
// Block computes a 128x128 tile of one (b,h).  4 waves; wave w covers
// rows [w*32, w*32+32).  K = 64 (two 16x16x32 MFMA steps).
// LDS rows padded to 72 bf16 (stride 36 banks -> 2-way conflict = free).
// Output layout: attn_reshaped[b,n,h,m] = ((b*N+n)*H+h)*N + m.
// ---------------------------------------------------------------------------
__global__ __launch_bounds__(256) void k_gram(const ushort* __restrict__ wunit,
                                              float* __restrict__ out1) {
    const int bh = blockIdx.y;
    const int b = bh >> 3, h = bh & 7;
    const int tn = blockIdx.x & 7;   // row tile (n)
    const int tm = blockIdx.x >> 3;  // col tile (m)
    __shared__ ushort lA[128][72];
    __shared__ ushort lB[128][72];
    const int t = threadIdx.x;
    const ushort* Ub = wunit + (size_t)bh * N_ * D_;

    {   // stage both 128x64 bf16 tiles, 16 B per thread per step, coalesced
        const uint4* gA = (const uint4*)(Ub + (size_t)tn * 128 * D_);
        const uint4* gB = (const uint4*)(Ub + (size_t)tm * 128 * D_);
        #pragma unroll
        for (int c = 0; c < 4; ++c) {
            const int idx = t + c * 256;        // [0,1024) 16B-chunks
            const int row = idx >> 3, col8 = (idx & 7) * 8;
            *(uint4*)&lA[row][col8] = gA[idx];
            *(uint4*)&lB[row][col8] = gB[idx];
        }
    }
    __syncthreads();

    const int wave = t >> 6, lane = t & 63;
    const int rbase = wave * 32;
    const int arow = lane & 15;
    const int kq = (lane >> 4) * 8;

    f32x4 acc[2][8];
    #pragma unroll
    for (int i = 0; i < 2; ++i)
        #pragma unroll
        for (int j = 0; j < 8; ++j) acc[i][j] = (f32x4){0.f, 0.f, 0.f, 0.f};

    #pragma unroll
    for (int kk = 0; kk < 2; ++kk) {
        const int ko = kk * 32 + kq;
        const short8 a0 = *(const short8*)&lA[rbase + arow][ko];
        const short8 a1 = *(const short8*)&lA[rbase + 16 + arow][ko];
        #pragma unroll
        for (int tc = 0; tc < 8; ++tc) {
            const short8 bfr = *(const short8*)&lB[tc * 16 + arow][ko];
            acc[0][tc] = __builtin_amdgcn_mfma_f32_16x16x32_bf16(
                a0, bfr, acc[0][tc], 0, 0, 0);
            acc[1][tc] = __builtin_amdgcn_mfma_f32_16x16x32_bf16(
                a1, bfr, acc[1][tc], 0, 0, 0);
        }
    }

    // epilogue: C/D layout col = lane&15, row = (lane>>4)*4 + reg
    const int col = lane & 15;
    const int rq = (lane >> 4) * 4;
    #pragma unroll
    for (int tr = 0; tr < 2; ++tr) {
        #pragma unroll
        for (int tc = 0; tc < 8; ++tc) {
            #pragma unroll
            for (int r = 0; r < 4; ++r) {
                const int n = tn * 128 + rbase + tr * 16 + rq + r;
                const int m = tm * 128 + tc * 16 + col;
                out1[((size_t)(b * N_ + n) * H_ + h) * N_ + m] =
                    (acc[tr][tc][r] + 1.0f) * 0.5f;
            }
        }
    }
}

// ---------------------------------------------------------------------------
extern "C" void kernel_launch(void* const* d_in, const int* in_sizes, int n_in,
                              void* d_out, int out_size, void* d_ws,
                              size_t ws_size, hipStream_t stream) {
    const float* q = (const float*)d_in[0];       // [B, N, H, D] fp32
    const float* temp = (const float*)d_in[1];    // [H, 1] fp32
    float* out0 = (float*)d_out;                                  // [B,N,H,D]
    float* out1 = out0 + (size_t)B_ * N_ * H_ * D_;               // [B,N,H,N]

    // workspace: w_unit bf16 (8 MB) + energy (256 KB) + Pi (256 KB)
    ushort* wunit = (ushort*)d_ws;
    float* energy = (float*)((char*)d_ws + (size_t)B_ * H_ * N_ * D_ * 2);
    float* Pi = energy + (size_t)B_ * H_ * N_;

    k_stats<<<B_ * H_, 256, 0, stream>>>(q, wunit, energy);
    k_pi<<<(B_ * N_) / 256, 256, 0, stream>>>(energy, temp, Pi);
    k_out<<<B_ * H_, 256, 0, stream>>>(q, Pi, out0);
    k_gram<<<dim3(64, B_ * H_), 256, 0, stream>>>(wunit, out1);
}

// Round 2
// 335.714 us; speedup vs baseline: 1.1490x; 1.1490x over previous
//
#include <hip/hip_runtime.h>
#include <hip/hip_bf16.h>

#define B_ 8
#define N_ 1024
#define H_ 8
#define D_ 64

typedef __attribute__((ext_vector_type(8))) short short8;
typedef __attribute__((ext_vector_type(4))) float f32x4;

// ---------------------------------------------------------------------------
// Zero the atomic-accumulator region of ws (ws is re-poisoned 0xAA each call).
// ---------------------------------------------------------------------------
__global__ __launch_bounds__(256) void k_zero(float* __restrict__ p, int n) {
    const int i = blockIdx.x * 256 + threadIdx.x;
    if (i < n) p[i] = 0.f;
}

// ---------------------------------------------------------------------------
// k_colsum: grid (64 bh, 8 chunks), 256 thr.  Each block covers 128 rows of
// one (b,h): accumulates column sums-of-squares (atomicAdd into colsum[bh][64])
// and writes the row-normalized bf16 w_unit rows (row ssq via 16-lane shfl).
// ---------------------------------------------------------------------------
__global__ __launch_bounds__(256) void k_colsum(const float* __restrict__ q,
                                                ushort* __restrict__ wunit,
                                                float* __restrict__ colsum) {
    const int bh = blockIdx.x, chunk = blockIdx.y;
    const int b = bh >> 3, h = bh & 7;
    const float* qb = q + (size_t)(b * N_ * H_ + h) * D_;
    __shared__ float red[16][64];
    const int t = threadIdx.x;
    const int ng = t >> 4;          // 16 row-groups
    const int dq = (t & 15) * 4;    // 4 consecutive d per thread
    float cx = 0.f, cy = 0.f, cz = 0.f, cw = 0.f;
    #pragma unroll
    for (int i = 0; i < 8; ++i) {
        const int n = chunk * 128 + ng + i * 16;
        const float4 v = *(const float4*)(qb + (size_t)n * (H_ * D_) + dq);
        cx += v.x * v.x; cy += v.y * v.y; cz += v.z * v.z; cw += v.w * v.w;
        float ss = v.x * v.x + v.y * v.y + v.z * v.z + v.w * v.w;
        ss += __shfl_xor(ss, 1, 16);
        ss += __shfl_xor(ss, 2, 16);
        ss += __shfl_xor(ss, 4, 16);
        ss += __shfl_xor(ss, 8, 16);
        const float invr = 1.0f / fmaxf(sqrtf(ss), 1e-12f);
        __hip_bfloat162 p0 =
            __float22bfloat162_rn(make_float2(v.x * invr, v.y * invr));
        __hip_bfloat162 p1 =
            __float22bfloat162_rn(make_float2(v.z * invr, v.w * invr));
        uint2 pk;
        pk.x = *(unsigned int*)&p0;
        pk.y = *(unsigned int*)&p1;
        *(uint2*)(wunit + ((size_t)bh * N_ + n) * D_ + dq) = pk;
    }
    red[ng][dq + 0] = cx; red[ng][dq + 1] = cy;
    red[ng][dq + 2] = cz; red[ng][dq + 3] = cw;
    __syncthreads();
    if (t < 64) {
        float s = 0.f;
        #pragma unroll
        for (int i = 0; i < 16; ++i) s += red[i][t];
        atomicAdd(&colsum[bh * 64 + t], s);
    }
}

// ---------------------------------------------------------------------------
// k_energy: grid (64 bh, 4 chunks), 256 thr, one row per thread.
// energy[bh][n] = sum_d q^2 / max(colsum_d, 1e-24)
// ---------------------------------------------------------------------------
__global__ __launch_bounds__(256) void k_energy(const float* __restrict__ q,
                                                const float* __restrict__ colsum,
                                                float* __restrict__ energy) {
    const int bh = blockIdx.x, chunk = blockIdx.y;
    const int b = bh >> 3, h = bh & 7;
    __shared__ float inv2[64];
    const int t = threadIdx.x;
    if (t < 64) inv2[t] = 1.0f / fmaxf(colsum[bh * 64 + t], 1e-24f);
    __syncthreads();
    const int n = chunk * 256 + t;
    const float4* row =
        (const float4*)(q + (size_t)(b * N_ * H_ + h) * D_ + (size_t)n * (H_ * D_));
    float e = 0.f;
    #pragma unroll
    for (int i = 0; i < 16; ++i) {
        const float4 v = row[i];
        e += v.x * v.x * inv2[4 * i + 0] + v.y * v.y * inv2[4 * i + 1] +
             v.z * v.z * inv2[4 * i + 2] + v.w * v.w * inv2[4 * i + 3];
    }
    energy[(size_t)bh * N_ + n] = e;
}

// ---------------------------------------------------------------------------
// k_pi: softmax over head dim per (b,n); also accumulates Pisum[bh] via
// wave-reduce + one atomicAdd per wave per h.
// ---------------------------------------------------------------------------
__global__ __launch_bounds__(256) void k_pi(const float* __restrict__ energy,
                                            const float* __restrict__ temp,
                                            float* __restrict__ Pi,
                                            float* __restrict__ Pisum) {
    const int idx = blockIdx.x * 256 + threadIdx.x;  // [0, B*N)
    const int b = idx >> 10, n = idx & (N_ - 1);
    float e[H_];
    float m = -1e30f;
    #pragma unroll
    for (int h = 0; h < H_; ++h) {
        e[h] = energy[(size_t)(b * H_ + h) * N_ + n] * temp[h];
        m = fmaxf(m, e[h]);
    }
    float s = 0.f;
    #pragma unroll
    for (int h = 0; h < H_; ++h) { e[h] = expf(e[h] - m); s += e[h]; }
    const float inv = 1.0f / s;
    #pragma unroll
    for (int h = 0; h < H_; ++h) {
        const float p = e[h] * inv;
        Pi[(size_t)(b * H_ + h) * N_ + n] = p;
        float w = p;
        #pragma unroll
        for (int off = 32; off; off >>= 1) w += __shfl_xor(w, off, 64);
        if ((threadIdx.x & 63) == 0) atomicAdd(&Pisum[b * H_ + h], w);
    }
}

// ---------------------------------------------------------------------------
// k_dots: grid (64 bh, 8 chunks): partial sums of Pi[n]*q^2 per d,
// atomicAdd into dots[bh][64].
// ---------------------------------------------------------------------------
__global__ __launch_bounds__(256) void k_dots(const float* __restrict__ q,
                                              const float* __restrict__ Pi,
                                              float* __restrict__ dots) {
    const int bh = blockIdx.x, chunk = blockIdx.y;
    const int b = bh >> 3, h = bh & 7;
    const float* qb = q + (size_t)(b * N_ * H_ + h) * D_;
    const float* Pib = Pi + (size_t)bh * N_;
    __shared__ float red[16][64];
    const int t = threadIdx.x, ng = t >> 4, dq = (t & 15) * 4;
    float cx = 0.f, cy = 0.f, cz = 0.f, cw = 0.f;
    #pragma unroll
    for (int i = 0; i < 8; ++i) {
        const int n = chunk * 128 + ng + i * 16;
        const float p = Pib[n];
        const float4 v = *(const float4*)(qb + (size_t)n * (H_ * D_) + dq);
        cx += p * v.x * v.x; cy += p * v.y * v.y;
        cz += p * v.z * v.z; cw += p * v.w * v.w;
    }
    red[ng][dq + 0] = cx; red[ng][dq + 1] = cy;
    red[ng][dq + 2] = cz; red[ng][dq + 3] = cw;
    __syncthreads();
    if (t < 64) {
        float s = 0.f;
        #pragma unroll
        for (int i = 0; i < 16; ++i) s += red[i][t];
        atomicAdd(&dots[bh * 64 + t], s);
    }
}

// ---------------------------------------------------------------------------
// k_attn: attnv[bh][d] = 1 / (1 + dots/(Pisum+eps)).  4096 values.
// ---------------------------------------------------------------------------
__global__ __launch_bounds__(256) void k_attn(const float* __restrict__ dots,
                                              const float* __restrict__ Pisum,
                                              float* __restrict__ attnv) {
    const int i = blockIdx.x * 256 + threadIdx.x;
    const int bh = i >> 6;
    const float invS = 1.0f / (Pisum[bh] + 1e-8f);
    attnv[i] = 1.0f / (1.0f + dots[i] * invS);
}

// ---------------------------------------------------------------------------
// k_outw: grid (64 bh, 4 chunks), one row per thread: out0 = -(q*Pi)*attn.
// ---------------------------------------------------------------------------
__global__ __launch_bounds__(256) void k_outw(const float* __restrict__ q,
                                              const float* __restrict__ Pi,
                                              const float* __restrict__ attnv,
                                              float* __restrict__ out0) {
    const int bh = blockIdx.x, chunk = blockIdx.y;
    const int b = bh >> 3, h = bh & 7;
    __shared__ float av[64];
    const int t = threadIdx.x;
    if (t < 64) av[t] = attnv[bh * 64 + t];
    __syncthreads();
    const int n = chunk * 256 + t;
    const float p = -Pi[(size_t)bh * N_ + n];
    const float4* row =
        (const float4*)(q + (size_t)(b * N_ * H_ + h) * D_ + (size_t)n * (H_ * D_));
    float4* orow = (float4*)(out0 + ((size_t)(b * N_ + n) * H_ + h) * D_);
    #pragma unroll
    for (int i = 0; i < 16; ++i) {
        const float4 v = row[i];
        orow[i] = make_float4(v.x * p * av[4 * i + 0], v.y * p * av[4 * i + 1],
                              v.z * p * av[4 * i + 2], v.w * p * av[4 * i + 3]);
    }
}

// ---------------------------------------------------------------------------
// k_gram: (w_unit @ w_unit^T + 1)*0.5 via bf16 MFMA, 128x128 tile/block.
// Epilogue bounces each wave's 16x128 strip through LDS so global stores are
// float4 with each instruction covering two full 512 B rows.
// ---------------------------------------------------------------------------
__global__ __launch_bounds__(256) void k_gram(const ushort* __restrict__ wunit,
                                              float* __restrict__ out1) {
    const int bh = blockIdx.y;
    const int b = bh >> 3, h = bh & 7;
    const int tn = blockIdx.x & 7, tm = blockIdx.x >> 3;
    __shared__ __align__(16) char smem[36864];
    ushort(*lA)[72] = (ushort(*)[72])smem;
    ushort(*lB)[72] = (ushort(*)[72])(smem + 18432);
    float* stg = (float*)smem;  // reused after MFMA phase
    const int t = threadIdx.x;
    const ushort* Ub = wunit + (size_t)bh * N_ * D_;

    {
        const uint4* gA = (const uint4*)(Ub + (size_t)tn * 128 * D_);
        const uint4* gB = (const uint4*)(Ub + (size_t)tm * 128 * D_);
        #pragma unroll
        for (int c = 0; c < 4; ++c) {
            const int idx = t + c * 256;
            const int row = idx >> 3, col8 = (idx & 7) * 8;
            *(uint4*)&lA[row][col8] = gA[idx];
            *(uint4*)&lB[row][col8] = gB[idx];
        }
    }
    __syncthreads();

    const int wave = t >> 6, lane = t & 63;
    const int rbase = wave * 32;
    const int arow = lane & 15;
    const int kq = (lane >> 4) * 8;

    f32x4 acc[2][8];
    #pragma unroll
    for (int i = 0; i < 2; ++i)
        #pragma unroll
        for (int j = 0; j < 8; ++j) acc[i][j] = (f32x4){0.f, 0.f, 0.f, 0.f};

    #pragma unroll
    for (int kk = 0; kk < 2; ++kk) {
        const int ko = kk * 32 + kq;
        const short8 a0 = *(const short8*)&lA[rbase + arow][ko];
        const short8 a1 = *(const short8*)&lA[rbase + 16 + arow][ko];
        #pragma unroll
        for (int tc = 0; tc < 8; ++tc) {
            const short8 bfr = *(const short8*)&lB[tc * 16 + arow][ko];
            acc[0][tc] = __builtin_amdgcn_mfma_f32_16x16x32_bf16(
                a0, bfr, acc[0][tc], 0, 0, 0);
            acc[1][tc] = __builtin_amdgcn_mfma_f32_16x16x32_bf16(
                a1, bfr, acc[1][tc], 0, 0, 0);
        }
    }
    __syncthreads();  // all waves done reading lA/lB before staging overwrite

    // Staging: rows padded to 132 floats (2-way bank aliasing on writes: free).
    float* ms = stg + wave * 2112;          // 16*132 floats per wave
    const int col = lane & 15, rq = (lane >> 4) * 4;
    #pragma unroll
    for (int tr = 0; tr < 2; ++tr) {
        #pragma unroll
        for (int tc = 0; tc < 8; ++tc)
            #pragma unroll
            for (int r = 0; r < 4; ++r)
                ms[(rq + r) * 132 + tc * 16 + col] =
                    (acc[tr][tc][r] + 1.0f) * 0.5f;
        // in-wave DS ordering guarantees write->read; lgkmcnt handles data dep
        #pragma unroll
        for (int i = 0; i < 8; ++i) {
            const int f = i * 64 + lane;
            const int r2 = f >> 5, c2 = f & 31;
            const float4 v = *(const float4*)&ms[r2 * 132 + c2 * 4];
            const int n = tn * 128 + wave * 32 + tr * 16 + r2;
            const int m = tm * 128 + c2 * 4;
            *(float4*)&out1[((size_t)(b * N_ + n) * H_ + h) * N_ + m] = v;
        }
    }
}

// ---------------------------------------------------------------------------
extern "C" void kernel_launch(void* const* d_in, const int* in_sizes, int n_in,
                              void* d_out, int out_size, void* d_ws,
                              size_t ws_size, hipStream_t stream) {
    const float* q = (const float*)d_in[0];     // [B, N, H, D] fp32
    const float* temp = (const float*)d_in[1];  // [H] fp32
    float* out0 = (float*)d_out;                       // [B,N,H,D]
    float* out1 = out0 + (size_t)B_ * N_ * H_ * D_;    // [B,N,H,N]

    char* ws = (char*)d_ws;
    ushort* wunit = (ushort*)ws;                        // 8,388,608 B
    float* Pi     = (float*)(ws + 8388608);             //   262,144 B
    float* energy = (float*)(ws + 8650752);             //   262,144 B
    float* colsum = (float*)(ws + 8912896);             //    16,384 B
    float* dots   = (float*)(ws + 8929280);             //    16,384 B
    float* Pisum  = (float*)(ws + 8945664);             //       256 B
    float* attnv  = (float*)(ws + 8945920);             //    16,384 B

    // zero colsum+dots+Pisum (contiguous 33,024 B = 8256 floats)
    k_zero<<<33, 256, 0, stream>>>(colsum, 8256);
    k_colsum<<<dim3(64, 8), 256, 0, stream>>>(q, wunit, colsum);
    k_energy<<<dim3(64, 4), 256, 0, stream>>>(q, colsum, energy);
    k_pi<<<32, 256, 0, stream>>>(energy, temp, Pi, Pisum);
    k_dots<<<dim3(64, 8), 256, 0, stream>>>(q, Pi, dots);
    k_attn<<<16, 256, 0, stream>>>(dots, Pisum, attnv);
    k_outw<<<dim3(64, 4), 256, 0, stream>>>(q, Pi, attnv, out0);
    k_gram<<<dim3(64, 64), 256, 0, stream>>>(wunit, out1);
}